// Round 1
// baseline (319.029 us; speedup 1.0000x reference)
//
#include <hip/hip_runtime.h>
#include <math.h>

// ---------- wave-level (64-lane) butterfly reductions ----------
__device__ __forceinline__ float wave_reduce_sum(float v) {
#pragma unroll
    for (int off = 32; off > 0; off >>= 1) v += __shfl_xor(v, off, 64);
    return v;
}
__device__ __forceinline__ float wave_reduce_max(float v) {
#pragma unroll
    for (int off = 32; off > 0; off >>= 1) v = fmaxf(v, __shfl_xor(v, off, 64));
    return v;
}
__device__ __forceinline__ int wave_reduce_sum_i(int v) {
#pragma unroll
    for (int off = 32; off > 0; off >>= 1) v += __shfl_xor(v, off, 64);
    return v;
}

// ---------- cross-entropy: one wave per row, per-block partial sums ----------
__global__ void ce_kernel(const float* __restrict__ preds,
                          const int* __restrict__ labels,
                          float* __restrict__ partials, int B, int C) {
    __shared__ float sh[4];
    const int wave = threadIdx.x >> 6, lane = threadIdx.x & 63;
    const int row = blockIdx.x * 4 + wave;
    float loss = 0.f;
    if (row < B) {
        const float* x = preds + (size_t)row * (size_t)C;
        float vals[8];
        int nv = 0;
        float m = -3.4e38f;
        for (int c = lane; c < C && nv < 8; c += 64) {
            float v = x[c];
            vals[nv++] = v;
            m = fmaxf(m, v);
        }
        m = wave_reduce_max(m);
        float s = 0.f;
        for (int i = 0; i < nv; i++) s += expf(vals[i] - m);
        s = wave_reduce_sum(s);
        const int label = labels[row];             // wave-uniform
        const int src = label & 63, idx = label >> 6;
        float cand = (idx < nv) ? vals[idx] : 0.f;
        float xl = __shfl(cand, src, 64);          // x[label]
        loss = logf(s) + m - xl;                   // -(x[l] - max - log(sumexp))
    }
    if (lane == 0) sh[wave] = loss;
    __syncthreads();
    if (threadIdx.x == 0) partials[blockIdx.x] = sh[0] + sh[1] + sh[2] + sh[3];
}

// ---------- physics score: one wave per row, row staged in LDS ----------
// score reduction: per-block sum of 4 rows' scores -> partials
__global__ void phys_kernel(const float* __restrict__ wglob,
                            float* __restrict__ partials, int B, int T) {
    extern __shared__ float lds[];     // 4 * T*3 floats
    __shared__ float shScore[4];
    const int wave = threadIdx.x >> 6, lane = threadIdx.x & 63;
    const int row = blockIdx.x * 4 + wave;
    const int N = T * 3;
    float* L = lds + wave * N;
    const bool active = (row < B);

    if (active) {
        const float4* src4 = (const float4*)(wglob + (size_t)row * (size_t)N);
        float4* dst4 = (float4*)L;
        const int n4 = N >> 2;                       // T*3 divisible by 4 (T%4==0)
        for (int i = lane; i < n4; i += 64) dst4[i] = src4[i];
    }
    __syncthreads();

    float score = 0.f;
    if (active) {
        const int kmax = (T + 63) >> 6;              // 8 for T=512
        float v0[8], v1[8], v2[8];
        float sum0 = 0, sum1 = 0, sum2 = 0, sq = 0;
        float mx0 = 0, mx1 = 0, mx2 = 0;
        int jerkcnt = 0;
        // pass 1: sums, sum-of-squares, max|.|, jerk exceed count (raw data only)
        for (int k = 0; k < kmax; k++) {
            const int t = lane + (k << 6);
            float a = 0, b = 0, c = 0;
            if (t < T) { a = L[t * 3 + 0]; b = L[t * 3 + 1]; c = L[t * 3 + 2]; }
            v0[k] = a; v1[k] = b; v2[k] = c;
            sum0 += a; sum1 += b; sum2 += c;
            sq += a * a + b * b + c * c;
            mx0 = fmaxf(mx0, fabsf(a));
            mx1 = fmaxf(mx1, fabsf(b));
            mx2 = fmaxf(mx2, fabsf(c));
            if (t < T - 4) {
                // jerk[i] = (w[i+4] - 2 w[i+2] + w[i]) / (2dt)^2, dt=0.02 -> *625
                float a2 = L[(t + 2) * 3 + 0], b2 = L[(t + 2) * 3 + 1], c2 = L[(t + 2) * 3 + 2];
                float a4 = L[(t + 4) * 3 + 0], b4 = L[(t + 4) * 3 + 1], c4 = L[(t + 4) * 3 + 2];
                jerkcnt += (fabsf(625.f * (a4 - 2.f * a2 + a)) > 5000.f);
                jerkcnt += (fabsf(625.f * (b4 - 2.f * b2 + b)) > 5000.f);
                jerkcnt += (fabsf(625.f * (c4 - 2.f * c2 + c)) > 5000.f);
            }
        }
        sum0 = wave_reduce_sum(sum0);
        sum1 = wave_reduce_sum(sum1);
        sum2 = wave_reduce_sum(sum2);
        sq   = wave_reduce_sum(sq);
        mx0  = wave_reduce_max(mx0);
        mx1  = wave_reduce_max(mx1);
        mx2  = wave_reduce_max(mx2);
        const float n = (float)T;
        const float m0 = sum0 / n, m1 = sum1 / n, m2 = sum2 / n;
        (void)m1; (void)m2;
        // tv = sum((w-mean)^2)/n  via identity (no cancellation: sq >> sum^2/n here)
        const float tv = (sq - (sum0 * sum0 + sum1 * sum1 + sum2 * sum2) / n) / n;

        // pass 2: near-max counts per channel + zero-crossing count (channel 0)
        int a0 = 0, a1 = 0, a2c = 0, zc = 0;
        for (int k = 0; k < kmax; k++) {
            const int t = lane + (k << 6);
            if (t < T) {
                a0  += (fabsf(fabsf(v0[k]) - mx0) < 0.01f);
                a1  += (fabsf(fabsf(v1[k]) - mx1) < 0.01f);
                a2c += (fabsf(fabsf(v2[k]) - mx2) < 0.01f);
                if (t < T - 1) {
                    float dxt = v0[k] - m0;
                    float dxn = L[(t + 1) * 3 + 0] - m0;
                    zc += (dxt * dxn < 0.f);
                }
            }
        }
        int pk1 = a0 | (a1 << 10) | (a2c << 20);
        int pk2 = zc | (jerkcnt << 16);
        pk1 = wave_reduce_sum_i(pk1);
        pk2 = wave_reduce_sum_i(pk2);
        a0 = pk1 & 1023; a1 = (pk1 >> 10) & 1023; a2c = (pk1 >> 20) & 1023;
        zc = pk2 & 0xffff; jerkcnt = pk2 >> 16;

        bool reject = (tv < 0.005f);
        const float fT = (float)T;
        if (mx0 >= 0.5f && (a0  / fT) > 0.2f) reject = true;
        if (mx1 >= 0.5f && (a1  / fT) > 0.2f) reject = true;
        if (mx2 >= 0.5f && (a2c / fT) > 0.2f) reject = true;
        // js[p95_idx] > 5000  <=>  count(>5000) >= jtot - p95_idx
        const int jtot = (T - 4) * 3;
        const int p95 = (int)((double)jtot * 0.95);
        if (jerkcnt >= jtot - p95) reject = true;

        const float s1 = tv > 10.f ? 90.f : (tv > 2.f ? 80.f : (tv > 0.5f ? 70.f : 58.f));
        const float zcr = zc / fT;
        const float s2 = zcr > 0.15f ? 85.f : (zcr > 0.07f ? 70.f : 55.f);
        score = floorf((s1 + s2) * 0.5f);
        if (reject) score = 0.f;
    }
    if (lane == 0) shScore[wave] = score;
    __syncthreads();
    if (threadIdx.x == 0)
        partials[blockIdx.x] = shScore[0] + shScore[1] + shScore[2] + shScore[3];
}

// ---------- final combine: sum partials, emit scalar loss ----------
__global__ void finalize_kernel(const float* __restrict__ p1, const float* __restrict__ p2,
                                int n1, int n2, float* __restrict__ out, int B) {
    __shared__ float sh1[4], sh2[4];
    const int tid = threadIdx.x;
    float s1 = 0.f, s2 = 0.f;
    for (int i = tid; i < n1; i += 256) s1 += p1[i];
    for (int i = tid; i < n2; i += 256) s2 += p2[i];
    s1 = wave_reduce_sum(s1);
    s2 = wave_reduce_sum(s2);
    const int wave = tid >> 6, lane = tid & 63;
    if (lane == 0) { sh1[wave] = s1; sh2[wave] = s2; }
    __syncthreads();
    if (tid == 0) {
        float task = (sh1[0] + sh1[1] + sh1[2] + sh1[3]) / (float)B;
        float pen  = 1.f - (sh2[0] + sh2[1] + sh2[2] + sh2[3]) / (100.f * (float)B);
        out[0] = task + 0.3f * pen;   // TASK_WEIGHT=1.0, PHYSICS_WEIGHT=0.3
    }
}

extern "C" void kernel_launch(void* const* d_in, const int* in_sizes, int n_in,
                              void* d_out, int out_size, void* d_ws, size_t ws_size,
                              hipStream_t stream) {
    const float* preds = (const float*)d_in[0];
    const int* labels  = (const int*)d_in[1];
    const float* imu   = (const float*)d_in[2];
    float* out = (float*)d_out;

    const int B = in_sizes[1];
    const int C = in_sizes[0] / B;
    const int T = in_sizes[2] / (3 * B);

    const int ceBlocks = (B + 3) / 4;
    const int phBlocks = (B + 3) / 4;
    float* p1 = (float*)d_ws;        // [ceBlocks] CE partial sums
    float* p2 = p1 + ceBlocks;       // [phBlocks] score partial sums

    ce_kernel<<<ceBlocks, 256, 0, stream>>>(preds, labels, p1, B, C);
    const size_t smem = (size_t)4 * (size_t)T * 3 * sizeof(float);
    phys_kernel<<<phBlocks, 256, smem, stream>>>(imu, p2, B, T);
    finalize_kernel<<<1, 256, 0, stream>>>(p1, p2, ceBlocks, phBlocks, out, B);
}

// Round 2
// 308.899 us; speedup vs baseline: 1.0328x; 1.0328x over previous
//
#include <hip/hip_runtime.h>
#include <math.h>

// ---------- wave-level (64-lane) butterfly reductions ----------
__device__ __forceinline__ float wave_reduce_sum(float v) {
#pragma unroll
    for (int off = 32; off > 0; off >>= 1) v += __shfl_xor(v, off, 64);
    return v;
}
__device__ __forceinline__ float wave_reduce_max(float v) {
#pragma unroll
    for (int off = 32; off > 0; off >>= 1) v = fmaxf(v, __shfl_xor(v, off, 64));
    return v;
}
__device__ __forceinline__ int wave_reduce_sum_i(int v) {
#pragma unroll
    for (int off = 32; off > 0; off >>= 1) v += __shfl_xor(v, off, 64);
    return v;
}

// ---------- cross-entropy: one wave per row ----------
// CT_C > 0: compile-time C (must be multiple of 64); CT_C == 0: runtime C.
template <int CT_C>
__global__ void ce_kernel(const float* __restrict__ preds,
                          const int* __restrict__ labels,
                          float* __restrict__ partials, int B, int C_rt) {
    __shared__ float sh[4];
    const int wave = threadIdx.x >> 6, lane = threadIdx.x & 63;
    const int row = blockIdx.x * 4 + wave;
    float loss = 0.f;
    if (row < B) {
        const int C = (CT_C > 0) ? CT_C : C_rt;
        constexpr int NV = (CT_C > 0) ? (CT_C / 64) : 16;
        const int nv = (CT_C > 0) ? NV : ((C_rt + 63) >> 6);
        const float* x = preds + (size_t)row * (size_t)C;
        float vals[NV];
        float m = -3.4e38f;
#pragma unroll
        for (int i = 0; i < NV; i++) {
            if (CT_C == 0 && i >= nv) break;
            const int c = lane + (i << 6);
            float v = (CT_C > 0 || c < C) ? x[c] : -3.4e38f;
            vals[i] = v;
            m = fmaxf(m, v);
        }
        m = wave_reduce_max(m);
        float s = 0.f;
#pragma unroll
        for (int i = 0; i < NV; i++) {
            if (CT_C == 0 && i >= nv) break;
            const int c = lane + (i << 6);
            if (CT_C > 0 || c < C) s += expf(vals[i] - m);
        }
        s = wave_reduce_sum(s);
        const int label = labels[row];             // wave-uniform
        const int src = label & 63, idx = label >> 6;
        float cand = vals[0];
#pragma unroll
        for (int i = 1; i < NV; i++) {
            if (CT_C == 0 && i >= nv) break;
            if (i == idx) cand = vals[i];          // idx is wave-uniform
        }
        float xl = __shfl(cand, src, 64);          // x[label]
        loss = logf(s) + m - xl;                   // -(x[l] - max - log(sumexp))
    }
    if (lane == 0) sh[wave] = loss;
    __syncthreads();
    if (threadIdx.x == 0) partials[blockIdx.x] = sh[0] + sh[1] + sh[2] + sh[3];
}

// ---------- physics score: one wave per row, row staged in LDS ----------
// CT_T > 0: compile-time T (multiple of 64); CT_T == 0: runtime T (<= 1024).
template <int CT_T>
__global__ void phys_kernel(const float* __restrict__ wglob,
                            float* __restrict__ partials, int B, int T_rt) {
    extern __shared__ float lds[];     // 4 * T*3 floats
    __shared__ float shScore[4];
    const int wave = threadIdx.x >> 6, lane = threadIdx.x & 63;
    const int row = blockIdx.x * 4 + wave;
    const int T = (CT_T > 0) ? CT_T : T_rt;
    const int N = T * 3;
    float* L = lds + wave * N;
    const bool active = (row < B);

    if (active) {
        const float4* src4 = (const float4*)(wglob + (size_t)row * (size_t)N);
        float4* dst4 = (float4*)L;
        const int n4 = N >> 2;                       // T*3 divisible by 4 (T%4==0)
        for (int i = lane; i < n4; i += 64) dst4[i] = src4[i];
    }
    __syncthreads();

    float score = 0.f;
    if (active) {
        constexpr int KMAX = (CT_T > 0) ? (CT_T + 63) / 64 : 16;
        const int kmax = (CT_T > 0) ? KMAX : ((T_rt + 63) >> 6);
        float v0[KMAX], v1[KMAX], v2[KMAX];
        float sum0 = 0, sum1 = 0, sum2 = 0, sq = 0;
        float mx0 = 0, mx1 = 0, mx2 = 0;
        int jerkcnt = 0;
        // pass 1: sums, sum-of-squares, max|.|, jerk exceed count (raw data only)
#pragma unroll
        for (int k = 0; k < KMAX; k++) {
            if (CT_T == 0 && k >= kmax) break;
            const int t = lane + (k << 6);
            float a = 0, b = 0, c = 0;
            if (CT_T > 0 || t < T) { a = L[t * 3 + 0]; b = L[t * 3 + 1]; c = L[t * 3 + 2]; }
            v0[k] = a; v1[k] = b; v2[k] = c;
            sum0 += a; sum1 += b; sum2 += c;
            sq += a * a + b * b + c * c;
            mx0 = fmaxf(mx0, fabsf(a));
            mx1 = fmaxf(mx1, fabsf(b));
            mx2 = fmaxf(mx2, fabsf(c));
            if (t < T - 4) {
                // jerk[i] = (w[i+4] - 2 w[i+2] + w[i]) / (2dt)^2, dt=0.02 -> *625
                float a2 = L[(t + 2) * 3 + 0], b2 = L[(t + 2) * 3 + 1], c2 = L[(t + 2) * 3 + 2];
                float a4 = L[(t + 4) * 3 + 0], b4 = L[(t + 4) * 3 + 1], c4 = L[(t + 4) * 3 + 2];
                jerkcnt += (fabsf(625.f * (a4 - 2.f * a2 + a)) > 5000.f);
                jerkcnt += (fabsf(625.f * (b4 - 2.f * b2 + b)) > 5000.f);
                jerkcnt += (fabsf(625.f * (c4 - 2.f * c2 + c)) > 5000.f);
            }
        }
        sum0 = wave_reduce_sum(sum0);
        sum1 = wave_reduce_sum(sum1);
        sum2 = wave_reduce_sum(sum2);
        sq   = wave_reduce_sum(sq);
        mx0  = wave_reduce_max(mx0);
        mx1  = wave_reduce_max(mx1);
        mx2  = wave_reduce_max(mx2);
        const float n = (float)T;
        const float m0 = sum0 / n;
        // tv = sum((w-mean)^2)/n  via identity (no cancellation risk here:
        // thresholds are hundreds of sigma from the data distribution)
        const float tv = (sq - (sum0 * sum0 + sum1 * sum1 + sum2 * sum2) / n) / n;

        // pass 2: near-max counts per channel + zero-crossing count (channel 0)
        int a0 = 0, a1 = 0, a2c = 0, zc = 0;
#pragma unroll
        for (int k = 0; k < KMAX; k++) {
            if (CT_T == 0 && k >= kmax) break;
            const int t = lane + (k << 6);
            if (CT_T > 0 || t < T) {
                a0  += (fabsf(fabsf(v0[k]) - mx0) < 0.01f);
                a1  += (fabsf(fabsf(v1[k]) - mx1) < 0.01f);
                a2c += (fabsf(fabsf(v2[k]) - mx2) < 0.01f);
                if (t < T - 1) {
                    float dxt = v0[k] - m0;
                    float dxn = L[(t + 1) * 3 + 0] - m0;
                    zc += (dxt * dxn < 0.f);
                }
            }
        }
        int pk1 = a0 | (a1 << 10) | (a2c << 20);
        int pk2 = zc | (jerkcnt << 16);
        pk1 = wave_reduce_sum_i(pk1);
        pk2 = wave_reduce_sum_i(pk2);
        a0 = pk1 & 1023; a1 = (pk1 >> 10) & 1023; a2c = (pk1 >> 20) & 1023;
        zc = pk2 & 0xffff; jerkcnt = pk2 >> 16;

        bool reject = (tv < 0.005f);
        const float fT = (float)T;
        if (mx0 >= 0.5f && (a0  / fT) > 0.2f) reject = true;
        if (mx1 >= 0.5f && (a1  / fT) > 0.2f) reject = true;
        if (mx2 >= 0.5f && (a2c / fT) > 0.2f) reject = true;
        // js[p95_idx] > 5000  <=>  count(>5000) >= jtot - p95_idx
        const int jtot = (T - 4) * 3;
        const int p95 = (int)((double)jtot * 0.95);
        if (jerkcnt >= jtot - p95) reject = true;

        const float s1 = tv > 10.f ? 90.f : (tv > 2.f ? 80.f : (tv > 0.5f ? 70.f : 58.f));
        const float zcr = zc / fT;
        const float s2 = zcr > 0.15f ? 85.f : (zcr > 0.07f ? 70.f : 55.f);
        score = floorf((s1 + s2) * 0.5f);
        if (reject) score = 0.f;
    }
    if (lane == 0) shScore[wave] = score;
    __syncthreads();
    if (threadIdx.x == 0)
        partials[blockIdx.x] = shScore[0] + shScore[1] + shScore[2] + shScore[3];
}

// ---------- final combine: sum partials, emit scalar loss ----------
__global__ void finalize_kernel(const float* __restrict__ p1, const float* __restrict__ p2,
                                int n1, int n2, float* __restrict__ out, int B) {
    __shared__ float sh1[4], sh2[4];
    const int tid = threadIdx.x;
    float s1 = 0.f, s2 = 0.f;
    for (int i = tid; i < n1; i += 256) s1 += p1[i];
    for (int i = tid; i < n2; i += 256) s2 += p2[i];
    s1 = wave_reduce_sum(s1);
    s2 = wave_reduce_sum(s2);
    const int wave = tid >> 6, lane = tid & 63;
    if (lane == 0) { sh1[wave] = s1; sh2[wave] = s2; }
    __syncthreads();
    if (tid == 0) {
        float task = (sh1[0] + sh1[1] + sh1[2] + sh1[3]) / (float)B;
        float pen  = 1.f - (sh2[0] + sh2[1] + sh2[2] + sh2[3]) / (100.f * (float)B);
        out[0] = task + 0.3f * pen;   // TASK_WEIGHT=1.0, PHYSICS_WEIGHT=0.3
    }
}

extern "C" void kernel_launch(void* const* d_in, const int* in_sizes, int n_in,
                              void* d_out, int out_size, void* d_ws, size_t ws_size,
                              hipStream_t stream) {
    const float* preds = (const float*)d_in[0];
    const int* labels  = (const int*)d_in[1];
    const float* imu   = (const float*)d_in[2];
    float* out = (float*)d_out;

    const int B = in_sizes[1];
    const int C = in_sizes[0] / B;
    const int T = in_sizes[2] / (3 * B);

    const int ceBlocks = (B + 3) / 4;
    const int phBlocks = (B + 3) / 4;
    float* p1 = (float*)d_ws;        // [ceBlocks] CE partial sums
    float* p2 = p1 + ceBlocks;       // [phBlocks] score partial sums

    // Specialized paths for the benchmarked shape (compile-time trip counts
    // -> full unroll -> private arrays stay in VGPRs, no scratch spill).
    if (C == 128) ce_kernel<128><<<ceBlocks, 256, 0, stream>>>(preds, labels, p1, B, C);
    else          ce_kernel<0><<<ceBlocks, 256, 0, stream>>>(preds, labels, p1, B, C);

    const size_t smem = (size_t)4 * (size_t)T * 3 * sizeof(float);
    if (T == 512) phys_kernel<512><<<phBlocks, 256, smem, stream>>>(imu, p2, B, T);
    else          phys_kernel<0><<<phBlocks, 256, smem, stream>>>(imu, p2, B, T);

    finalize_kernel<<<1, 256, 0, stream>>>(p1, p2, ceBlocks, phBlocks, out, B);
}

// Round 3
// 304.918 us; speedup vs baseline: 1.0463x; 1.0131x over previous
//
#include <hip/hip_runtime.h>
#include <math.h>

// ===================== DPP wave-64 reductions (VALU pipe, no LDS) ==========
// row_shr:1/2/4/8 prefix within 16-lane rows, then row_bcast15 + row_bcast31.
// Total lives in lane 63; readlane broadcasts to SGPR (wave-uniform).
template <int CTRL>
__device__ __forceinline__ float dpp_zero_f(float x) {   // invalid lanes -> 0
    return __int_as_float(__builtin_amdgcn_update_dpp(
        0, __float_as_int(x), CTRL, 0xf, 0xf, true));
}
template <int CTRL>
__device__ __forceinline__ float dpp_self_f(float x) {   // invalid lanes -> own x
    return __int_as_float(__builtin_amdgcn_update_dpp(
        __float_as_int(x), __float_as_int(x), CTRL, 0xf, 0xf, false));
}
template <int CTRL>
__device__ __forceinline__ int dpp_zero_i(int x) {
    return __builtin_amdgcn_update_dpp(0, x, CTRL, 0xf, 0xf, true);
}

__device__ __forceinline__ float dpp_sum_f(float x) {
    x += dpp_zero_f<0x111>(x);   // row_shr:1
    x += dpp_zero_f<0x112>(x);   // row_shr:2
    x += dpp_zero_f<0x114>(x);   // row_shr:4
    x += dpp_zero_f<0x118>(x);   // row_shr:8  -> lane15/31/47/63 = row sums
    x += dpp_zero_f<0x142>(x);   // row_bcast15 -> lane31 = r0+r1, lane63 = r2+r3
    x += dpp_zero_f<0x143>(x);   // row_bcast31 -> lane63 = total
    return __int_as_float(__builtin_amdgcn_readlane(__float_as_int(x), 63));
}
__device__ __forceinline__ float dpp_max_f(float x) {    // safe for negatives
    x = fmaxf(x, dpp_self_f<0x111>(x));
    x = fmaxf(x, dpp_self_f<0x112>(x));
    x = fmaxf(x, dpp_self_f<0x114>(x));
    x = fmaxf(x, dpp_self_f<0x118>(x));
    x = fmaxf(x, dpp_self_f<0x142>(x));
    x = fmaxf(x, dpp_self_f<0x143>(x));
    return __int_as_float(__builtin_amdgcn_readlane(__float_as_int(x), 63));
}
__device__ __forceinline__ int dpp_sum_i(int x) {
    x += dpp_zero_i<0x111>(x);
    x += dpp_zero_i<0x112>(x);
    x += dpp_zero_i<0x114>(x);
    x += dpp_zero_i<0x118>(x);
    x += dpp_zero_i<0x142>(x);
    x += dpp_zero_i<0x143>(x);
    return __builtin_amdgcn_readlane(x, 63);
}

// ===================== fused CE + physics kernel ===========================
// One wave per row (4 rows/block). CE runs while the imu staging loads are in
// flight (independent of LDS); physics uses the LDS-staged row afterwards.
template <int CT_T, int CT_C>
__global__ void fused_kernel(const float* __restrict__ imu,
                             const float* __restrict__ preds,
                             const int* __restrict__ labels,
                             float* __restrict__ taskP,
                             float* __restrict__ scoreP,
                             int B, int T_rt, int C_rt) {
    extern __shared__ float lds[];                 // 4 * T*3 floats
    __shared__ float shT[4], shS[4];
    const int wave = threadIdx.x >> 6, lane = threadIdx.x & 63;
    const int row = blockIdx.x * 4 + wave;
    const int T = (CT_T > 0) ? CT_T : T_rt;
    const int N = T * 3;
    float* L = lds + wave * N;
    const bool active = (row < B);                 // wave-uniform

    // ---- stage imu row -> LDS (coalesced float4, issues the HBM long pole)
    if (active) {
        const float4* src4 = (const float4*)(imu + (size_t)row * (size_t)N);
        float4* dst4 = (float4*)L;
        const int n4 = N >> 2;
        for (int i = lane; i < n4; i += 64) dst4[i] = src4[i];
    }

    // ---- cross-entropy for the same row (no LDS dependency)
    float loss = 0.f;
    if (active) {
        const int C = (CT_C > 0) ? CT_C : C_rt;
        constexpr int NV = (CT_C > 0) ? (CT_C / 64) : 16;
        const int nv = (CT_C > 0) ? NV : ((C_rt + 63) >> 6);
        const float* x = preds + (size_t)row * (size_t)C;
        float vals[NV];
        float m = -3.4e38f;
#pragma unroll
        for (int i = 0; i < NV; i++) {
            if (CT_C == 0 && i >= nv) break;
            const int c = lane + (i << 6);
            float v = (CT_C > 0 || c < C) ? x[c] : -3.4e38f;
            vals[i] = v;
            m = fmaxf(m, v);
        }
        m = dpp_max_f(m);
        float s = 0.f;
#pragma unroll
        for (int i = 0; i < NV; i++) {
            if (CT_C == 0 && i >= nv) break;
            const int c = lane + (i << 6);
            if (CT_C > 0 || c < C) s += expf(vals[i] - m);
        }
        s = dpp_sum_f(s);
        const int label = labels[row];             // wave-uniform
        const int src = label & 63, idx = label >> 6;
        float cand = vals[0];
#pragma unroll
        for (int i = 1; i < NV; i++) {
            if (CT_C == 0 && i >= nv) break;
            if (i == idx) cand = vals[i];          // idx wave-uniform
        }
        float xl = __shfl(cand, src, 64);          // x[label]
        loss = logf(s) + m - xl;
    }
    __syncthreads();                               // staging visible

    // ---- physics score
    float score = 0.f;
    if (active) {
        constexpr int KMAX = (CT_T > 0) ? (CT_T + 63) / 64 : 16;
        const int kmax = (CT_T > 0) ? KMAX : ((T_rt + 63) >> 6);
        float v0[KMAX], v1[KMAX], v2[KMAX];
        float sum0 = 0, sum1 = 0, sum2 = 0, sq = 0;
        float mx0 = 0, mx1 = 0, mx2 = 0;
        int jerkcnt = 0;
        // pass 1: sums, sum-of-squares, max|.|, jerk-exceed count
#pragma unroll
        for (int k = 0; k < KMAX; k++) {
            if (CT_T == 0 && k >= kmax) break;
            const int t = lane + (k << 6);
            float a = 0, b = 0, c = 0;
            if (CT_T > 0 || t < T) { a = L[t * 3 + 0]; b = L[t * 3 + 1]; c = L[t * 3 + 2]; }
            v0[k] = a; v1[k] = b; v2[k] = c;
            sum0 += a; sum1 += b; sum2 += c;
            sq += a * a + b * b + c * c;
            mx0 = fmaxf(mx0, fabsf(a));
            mx1 = fmaxf(mx1, fabsf(b));
            mx2 = fmaxf(mx2, fabsf(c));
            if (t < T - 4) {
                // jerk = (w[t+4] - 2 w[t+2] + w[t]) / (2dt)^2, dt=0.02 -> *625
                float a2 = L[(t + 2) * 3 + 0], b2 = L[(t + 2) * 3 + 1], c2 = L[(t + 2) * 3 + 2];
                float a4 = L[(t + 4) * 3 + 0], b4 = L[(t + 4) * 3 + 1], c4 = L[(t + 4) * 3 + 2];
                jerkcnt += (fabsf(625.f * (a4 - 2.f * a2 + a)) > 5000.f);
                jerkcnt += (fabsf(625.f * (b4 - 2.f * b2 + b)) > 5000.f);
                jerkcnt += (fabsf(625.f * (c4 - 2.f * c2 + c)) > 5000.f);
            }
        }
        sum0 = dpp_sum_f(sum0);
        sum1 = dpp_sum_f(sum1);
        sum2 = dpp_sum_f(sum2);
        sq   = dpp_sum_f(sq);
        mx0  = dpp_max_f(mx0);
        mx1  = dpp_max_f(mx1);
        mx2  = dpp_max_f(mx2);
        const float n = (float)T;
        const float m0 = sum0 / n;
        // tv via sum-of-squares identity (thresholds are >15 sigma away)
        const float tv = (sq - (sum0 * sum0 + sum1 * sum1 + sum2 * sum2) / n) / n;

        // pass 2: near-max counts + zero-crossing count (channel 0)
        int a0 = 0, a1 = 0, a2c = 0, zc = 0;
#pragma unroll
        for (int k = 0; k < KMAX; k++) {
            if (CT_T == 0 && k >= kmax) break;
            const int t = lane + (k << 6);
            if (CT_T > 0 || t < T) {
                a0  += (fabsf(fabsf(v0[k]) - mx0) < 0.01f);
                a1  += (fabsf(fabsf(v1[k]) - mx1) < 0.01f);
                a2c += (fabsf(fabsf(v2[k]) - mx2) < 0.01f);
                if (t < T - 1) {
                    float dxt = v0[k] - m0;
                    float dxn = L[(t + 1) * 3 + 0] - m0;
                    zc += (dxt * dxn < 0.f);
                }
            }
        }
        int pk1 = a0 | (a1 << 10) | (a2c << 20);
        int pk2 = zc | (jerkcnt << 16);
        pk1 = dpp_sum_i(pk1);
        pk2 = dpp_sum_i(pk2);
        a0 = pk1 & 1023; a1 = (pk1 >> 10) & 1023; a2c = (pk1 >> 20) & 1023;
        zc = pk2 & 0xffff; jerkcnt = pk2 >> 16;

        bool reject = (tv < 0.005f);
        const float fT = (float)T;
        if (mx0 >= 0.5f && (a0  / fT) > 0.2f) reject = true;
        if (mx1 >= 0.5f && (a1  / fT) > 0.2f) reject = true;
        if (mx2 >= 0.5f && (a2c / fT) > 0.2f) reject = true;
        // js[p95_idx] > 5000  <=>  count(>5000) >= jtot - p95_idx
        const int jtot = (T - 4) * 3;
        const int p95 = (int)((double)jtot * 0.95);
        if (jerkcnt >= jtot - p95) reject = true;

        const float s1 = tv > 10.f ? 90.f : (tv > 2.f ? 80.f : (tv > 0.5f ? 70.f : 58.f));
        const float zcr = zc / fT;
        const float s2 = zcr > 0.15f ? 85.f : (zcr > 0.07f ? 70.f : 55.f);
        score = floorf((s1 + s2) * 0.5f);
        if (reject) score = 0.f;
    }

    if (lane == 0) { shT[wave] = loss; shS[wave] = score; }
    __syncthreads();
    if (threadIdx.x == 0) {
        taskP[blockIdx.x]  = shT[0] + shT[1] + shT[2] + shT[3];
        scoreP[blockIdx.x] = shS[0] + shS[1] + shS[2] + shS[3];
    }
}

// ===================== final combine ======================================
__device__ __forceinline__ float wave_reduce_sum_shfl(float v) {
#pragma unroll
    for (int off = 32; off > 0; off >>= 1) v += __shfl_xor(v, off, 64);
    return v;
}

__global__ void finalize_kernel(const float* __restrict__ p1, const float* __restrict__ p2,
                                int n1, int n2, float* __restrict__ out, int B) {
    __shared__ float sh1[4], sh2[4];
    const int tid = threadIdx.x;
    float s1 = 0.f, s2 = 0.f;
    for (int i = tid; i < n1; i += 256) s1 += p1[i];
    for (int i = tid; i < n2; i += 256) s2 += p2[i];
    s1 = wave_reduce_sum_shfl(s1);
    s2 = wave_reduce_sum_shfl(s2);
    const int wave = tid >> 6, lane = tid & 63;
    if (lane == 0) { sh1[wave] = s1; sh2[wave] = s2; }
    __syncthreads();
    if (tid == 0) {
        float task = (sh1[0] + sh1[1] + sh1[2] + sh1[3]) / (float)B;
        float pen  = 1.f - (sh2[0] + sh2[1] + sh2[2] + sh2[3]) / (100.f * (float)B);
        out[0] = task + 0.3f * pen;   // TASK_WEIGHT=1.0, PHYSICS_WEIGHT=0.3
    }
}

extern "C" void kernel_launch(void* const* d_in, const int* in_sizes, int n_in,
                              void* d_out, int out_size, void* d_ws, size_t ws_size,
                              hipStream_t stream) {
    const float* preds = (const float*)d_in[0];
    const int* labels  = (const int*)d_in[1];
    const float* imu   = (const float*)d_in[2];
    float* out = (float*)d_out;

    const int B = in_sizes[1];
    const int C = in_sizes[0] / B;
    const int T = in_sizes[2] / (3 * B);

    const int blocks = (B + 3) / 4;
    float* p1 = (float*)d_ws;        // [blocks] CE partial sums
    float* p2 = p1 + blocks;         // [blocks] score partial sums

    const size_t smem = (size_t)4 * (size_t)T * 3 * sizeof(float);
    if (T == 512 && C == 128)
        fused_kernel<512, 128><<<blocks, 256, smem, stream>>>(imu, preds, labels, p1, p2, B, T, C);
    else
        fused_kernel<0, 0><<<blocks, 256, smem, stream>>>(imu, preds, labels, p1, p2, B, T, C);

    finalize_kernel<<<1, 256, 0, stream>>>(p1, p2, blocks, blocks, out, B);
}

// Round 4
// 297.710 us; speedup vs baseline: 1.0716x; 1.0242x over previous
//
#include <hip/hip_runtime.h>
#include <math.h>

// ===================== DPP wave-64 reductions (VALU pipe, no LDS) ==========
template <int CTRL>
__device__ __forceinline__ float dpp_zero_f(float x) {   // invalid lanes -> 0
    return __int_as_float(__builtin_amdgcn_update_dpp(
        0, __float_as_int(x), CTRL, 0xf, 0xf, true));
}
template <int CTRL>
__device__ __forceinline__ float dpp_self_f(float x) {   // invalid lanes -> own x
    return __int_as_float(__builtin_amdgcn_update_dpp(
        __float_as_int(x), __float_as_int(x), CTRL, 0xf, 0xf, false));
}
template <int CTRL>
__device__ __forceinline__ int dpp_zero_i(int x) {
    return __builtin_amdgcn_update_dpp(0, x, CTRL, 0xf, 0xf, true);
}

__device__ __forceinline__ float dpp_sum_f(float x) {
    x += dpp_zero_f<0x111>(x);   // row_shr:1
    x += dpp_zero_f<0x112>(x);   // row_shr:2
    x += dpp_zero_f<0x114>(x);   // row_shr:4
    x += dpp_zero_f<0x118>(x);   // row_shr:8
    x += dpp_zero_f<0x142>(x);   // row_bcast15
    x += dpp_zero_f<0x143>(x);   // row_bcast31 -> lane63 = total
    return __int_as_float(__builtin_amdgcn_readlane(__float_as_int(x), 63));
}
__device__ __forceinline__ float dpp_max_f(float x) {    // safe for negatives
    x = fmaxf(x, dpp_self_f<0x111>(x));
    x = fmaxf(x, dpp_self_f<0x112>(x));
    x = fmaxf(x, dpp_self_f<0x114>(x));
    x = fmaxf(x, dpp_self_f<0x118>(x));
    x = fmaxf(x, dpp_self_f<0x142>(x));
    x = fmaxf(x, dpp_self_f<0x143>(x));
    return __int_as_float(__builtin_amdgcn_readlane(__float_as_int(x), 63));
}
__device__ __forceinline__ int dpp_sum_i(int x) {
    x += dpp_zero_i<0x111>(x);
    x += dpp_zero_i<0x112>(x);
    x += dpp_zero_i<0x114>(x);
    x += dpp_zero_i<0x118>(x);
    x += dpp_zero_i<0x142>(x);
    x += dpp_zero_i<0x143>(x);
    return __builtin_amdgcn_readlane(x, 63);
}

// ===================== specialized T=512,C=128: zero-LDS, register-chunked ==
// One wave per row. Lane i owns timesteps [8i, 8i+8); loads 12 timesteps
// (36 floats, 9 float4) to cover jerk's t+4 and zcr's t+1 lookahead.
// No LDS staging, no DS-pipe reads -- pure global stream + VALU + DPP.
__global__ void fused_reg_kernel(const float* __restrict__ imu,
                                 const float* __restrict__ preds,
                                 const int* __restrict__ labels,
                                 float* __restrict__ taskP,
                                 float* __restrict__ scoreP, int B) {
    constexpr int T = 512, C = 128, N = T * 3;
    __shared__ float shT[4], shS[4];
    const int wave = threadIdx.x >> 6, lane = threadIdx.x & 63;
    const int row = blockIdx.x * 4 + wave;
    float loss = 0.f, score = 0.f;

    if (row < B) {
        // ---- cross-entropy (C=128: 2 elements/lane) ----
        const float* x = preds + (size_t)row * C;
        const float c0 = x[lane], c1 = x[lane + 64];
        const float m = dpp_max_f(fmaxf(c0, c1));
        const float s = dpp_sum_f(expf(c0 - m) + expf(c1 - m));
        const int label = labels[row];                 // wave-uniform
        const float cand = ((label >> 6) == 0) ? c0 : c1;
        const float xl = __shfl(cand, label & 63, 64); // x[label]
        loss = logf(s) + m - xl;

        // ---- load this lane's chunk: floats [24*lane, 24*lane+36) ----
        const float* wr = imu + (size_t)row * N;
        float f[36];
#pragma unroll
        for (int j = 0; j < 9; j++) {
            int off = lane * 24 + j * 4;
            if (off > N - 4) off = N - 4;   // clamp lane 63 tail in-bounds;
                                            // lane 63 never consumes f[24..35]
            const float4 q = *(const float4*)(wr + off);
            f[j * 4 + 0] = q.x; f[j * 4 + 1] = q.y;
            f[j * 4 + 2] = q.z; f[j * 4 + 3] = q.w;
        }

        // ---- pass 1: sums, sumsq, max|.|, jerk-exceed count ----
        const int t0 = lane * 8;
        float sum0 = 0, sum1 = 0, sum2 = 0, sq = 0;
        float mx0 = 0, mx1 = 0, mx2 = 0;
        int jerkcnt = 0;
#pragma unroll
        for (int j = 0; j < 8; j++) {
            const float a = f[3 * j], b = f[3 * j + 1], c = f[3 * j + 2];
            sum0 += a; sum1 += b; sum2 += c;
            sq = fmaf(a, a, fmaf(b, b, fmaf(c, c, sq)));
            mx0 = fmaxf(mx0, fabsf(a));
            mx1 = fmaxf(mx1, fabsf(b));
            mx2 = fmaxf(mx2, fabsf(c));
            if (t0 + j < T - 4) {
                // jerk = (w[t+4] - 2 w[t+2] + w[t]) * 625  (dt=0.02)
                jerkcnt += (fabsf(625.f * (f[3*(j+4)+0] - 2.f * f[3*(j+2)+0] + a)) > 5000.f);
                jerkcnt += (fabsf(625.f * (f[3*(j+4)+1] - 2.f * f[3*(j+2)+1] + b)) > 5000.f);
                jerkcnt += (fabsf(625.f * (f[3*(j+4)+2] - 2.f * f[3*(j+2)+2] + c)) > 5000.f);
            }
        }
        sum0 = dpp_sum_f(sum0);
        sum1 = dpp_sum_f(sum1);
        sum2 = dpp_sum_f(sum2);
        sq   = dpp_sum_f(sq);
        mx0  = dpp_max_f(mx0);
        mx1  = dpp_max_f(mx1);
        mx2  = dpp_max_f(mx2);
        const float n = (float)T;
        const float m0 = sum0 / n;
        // tv via sum-of-squares identity (thresholds are >15 sigma away)
        const float tv = (sq - (sum0 * sum0 + sum1 * sum1 + sum2 * sum2) / n) / n;

        // ---- pass 2: near-max counts + zero crossings (channel 0) ----
        int a0 = 0, a1 = 0, a2c = 0, zc = 0;
#pragma unroll
        for (int j = 0; j < 8; j++) {
            a0  += (fabsf(fabsf(f[3 * j + 0]) - mx0) < 0.01f);
            a1  += (fabsf(fabsf(f[3 * j + 1]) - mx1) < 0.01f);
            a2c += (fabsf(fabsf(f[3 * j + 2]) - mx2) < 0.01f);
            if (t0 + j < T - 1) {
                const float dxt = f[3 * j + 0] - m0;
                const float dxn = f[3 * j + 3] - m0;
                zc += (dxt * dxn < 0.f);
            }
        }
        int pk1 = a0 | (a1 << 10) | (a2c << 20);
        int pk2 = zc | (jerkcnt << 16);
        pk1 = dpp_sum_i(pk1);
        pk2 = dpp_sum_i(pk2);
        a0 = pk1 & 1023; a1 = (pk1 >> 10) & 1023; a2c = (pk1 >> 20) & 1023;
        zc = pk2 & 0xffff; jerkcnt = pk2 >> 16;

        bool reject = (tv < 0.005f);
        const float fT = (float)T;
        if (mx0 >= 0.5f && (a0  / fT) > 0.2f) reject = true;
        if (mx1 >= 0.5f && (a1  / fT) > 0.2f) reject = true;
        if (mx2 >= 0.5f && (a2c / fT) > 0.2f) reject = true;
        // js[p95_idx] > 5000  <=>  count(>5000) >= jtot - p95_idx
        const int jtot = (T - 4) * 3;
        const int p95 = (int)((double)jtot * 0.95);
        if (jerkcnt >= jtot - p95) reject = true;

        const float s1 = tv > 10.f ? 90.f : (tv > 2.f ? 80.f : (tv > 0.5f ? 70.f : 58.f));
        const float zcr = zc / fT;
        const float s2 = zcr > 0.15f ? 85.f : (zcr > 0.07f ? 70.f : 55.f);
        score = floorf((s1 + s2) * 0.5f);
        if (reject) score = 0.f;
    }

    if (lane == 0) { shT[wave] = loss; shS[wave] = score; }
    __syncthreads();
    if (threadIdx.x == 0) {
        taskP[blockIdx.x]  = shT[0] + shT[1] + shT[2] + shT[3];
        scoreP[blockIdx.x] = shS[0] + shS[1] + shS[2] + shS[3];
    }
}

// ===================== generic fallback (LDS-staged, runtime T/C) ==========
__global__ void fused_generic_kernel(const float* __restrict__ imu,
                                     const float* __restrict__ preds,
                                     const int* __restrict__ labels,
                                     float* __restrict__ taskP,
                                     float* __restrict__ scoreP,
                                     int B, int T, int C) {
    extern __shared__ float lds[];
    __shared__ float shT[4], shS[4];
    const int wave = threadIdx.x >> 6, lane = threadIdx.x & 63;
    const int row = blockIdx.x * 4 + wave;
    const int N = T * 3;
    float* L = lds + wave * N;
    const bool active = (row < B);

    if (active) {
        const float4* src4 = (const float4*)(imu + (size_t)row * (size_t)N);
        float4* dst4 = (float4*)L;
        const int n4 = N >> 2;
        for (int i = lane; i < n4; i += 64) dst4[i] = src4[i];
    }
    float loss = 0.f;
    if (active) {
        const float* x = preds + (size_t)row * (size_t)C;
        float m = -3.4e38f;
        for (int c = lane; c < C; c += 64) m = fmaxf(m, x[c]);
        m = dpp_max_f(m);
        float s = 0.f;
        for (int c = lane; c < C; c += 64) s += expf(x[c] - m);
        s = dpp_sum_f(s);
        const int label = labels[row];
        float xl = (lane == 0) ? x[label] : 0.f;
        xl = __shfl(xl, 0, 64);
        loss = logf(s) + m - xl;
    }
    __syncthreads();
    float score = 0.f;
    if (active) {
        float sum0 = 0, sum1 = 0, sum2 = 0, sq = 0;
        float mx0 = 0, mx1 = 0, mx2 = 0;
        int jerkcnt = 0;
        for (int t = lane; t < T; t += 64) {
            float a = L[t * 3], b = L[t * 3 + 1], c = L[t * 3 + 2];
            sum0 += a; sum1 += b; sum2 += c;
            sq += a * a + b * b + c * c;
            mx0 = fmaxf(mx0, fabsf(a));
            mx1 = fmaxf(mx1, fabsf(b));
            mx2 = fmaxf(mx2, fabsf(c));
            if (t < T - 4) {
                float a2 = L[(t+2)*3], b2 = L[(t+2)*3+1], c2 = L[(t+2)*3+2];
                float a4 = L[(t+4)*3], b4 = L[(t+4)*3+1], c4 = L[(t+4)*3+2];
                jerkcnt += (fabsf(625.f * (a4 - 2.f*a2 + a)) > 5000.f);
                jerkcnt += (fabsf(625.f * (b4 - 2.f*b2 + b)) > 5000.f);
                jerkcnt += (fabsf(625.f * (c4 - 2.f*c2 + c)) > 5000.f);
            }
        }
        sum0 = dpp_sum_f(sum0); sum1 = dpp_sum_f(sum1); sum2 = dpp_sum_f(sum2);
        sq = dpp_sum_f(sq);
        mx0 = dpp_max_f(mx0); mx1 = dpp_max_f(mx1); mx2 = dpp_max_f(mx2);
        const float n = (float)T;
        const float m0 = sum0 / n;
        const float tv = (sq - (sum0*sum0 + sum1*sum1 + sum2*sum2) / n) / n;
        int a0 = 0, a1 = 0, a2c = 0, zc = 0;
        for (int t = lane; t < T; t += 64) {
            a0  += (fabsf(fabsf(L[t*3+0]) - mx0) < 0.01f);
            a1  += (fabsf(fabsf(L[t*3+1]) - mx1) < 0.01f);
            a2c += (fabsf(fabsf(L[t*3+2]) - mx2) < 0.01f);
            if (t < T - 1) {
                float dxt = L[t*3] - m0, dxn = L[(t+1)*3] - m0;
                zc += (dxt * dxn < 0.f);
            }
        }
        int pk1 = a0 | (a1 << 10) | (a2c << 20);
        int pk2 = zc | (jerkcnt << 16);
        pk1 = dpp_sum_i(pk1); pk2 = dpp_sum_i(pk2);
        a0 = pk1 & 1023; a1 = (pk1 >> 10) & 1023; a2c = (pk1 >> 20) & 1023;
        zc = pk2 & 0xffff; jerkcnt = pk2 >> 16;
        bool reject = (tv < 0.005f);
        const float fT = (float)T;
        if (mx0 >= 0.5f && (a0  / fT) > 0.2f) reject = true;
        if (mx1 >= 0.5f && (a1  / fT) > 0.2f) reject = true;
        if (mx2 >= 0.5f && (a2c / fT) > 0.2f) reject = true;
        const int jtot = (T - 4) * 3;
        const int p95 = (int)((double)jtot * 0.95);
        if (jerkcnt >= jtot - p95) reject = true;
        const float s1 = tv > 10.f ? 90.f : (tv > 2.f ? 80.f : (tv > 0.5f ? 70.f : 58.f));
        const float zcr = zc / fT;
        const float s2 = zcr > 0.15f ? 85.f : (zcr > 0.07f ? 70.f : 55.f);
        score = floorf((s1 + s2) * 0.5f);
        if (reject) score = 0.f;
    }
    if (lane == 0) { shT[wave] = loss; shS[wave] = score; }
    __syncthreads();
    if (threadIdx.x == 0) {
        taskP[blockIdx.x]  = shT[0] + shT[1] + shT[2] + shT[3];
        scoreP[blockIdx.x] = shS[0] + shS[1] + shS[2] + shS[3];
    }
}

// ===================== final combine ======================================
__device__ __forceinline__ float wave_reduce_sum_shfl(float v) {
#pragma unroll
    for (int off = 32; off > 0; off >>= 1) v += __shfl_xor(v, off, 64);
    return v;
}

__global__ void finalize_kernel(const float* __restrict__ p1, const float* __restrict__ p2,
                                int n1, int n2, float* __restrict__ out, int B) {
    __shared__ float sh1[4], sh2[4];
    const int tid = threadIdx.x;
    float s1 = 0.f, s2 = 0.f;
    for (int i = tid; i < n1; i += 256) s1 += p1[i];
    for (int i = tid; i < n2; i += 256) s2 += p2[i];
    s1 = wave_reduce_sum_shfl(s1);
    s2 = wave_reduce_sum_shfl(s2);
    const int wave = tid >> 6, lane = tid & 63;
    if (lane == 0) { sh1[wave] = s1; sh2[wave] = s2; }
    __syncthreads();
    if (tid == 0) {
        float task = (sh1[0] + sh1[1] + sh1[2] + sh1[3]) / (float)B;
        float pen  = 1.f - (sh2[0] + sh2[1] + sh2[2] + sh2[3]) / (100.f * (float)B);
        out[0] = task + 0.3f * pen;   // TASK_WEIGHT=1.0, PHYSICS_WEIGHT=0.3
    }
}

extern "C" void kernel_launch(void* const* d_in, const int* in_sizes, int n_in,
                              void* d_out, int out_size, void* d_ws, size_t ws_size,
                              hipStream_t stream) {
    const float* preds = (const float*)d_in[0];
    const int* labels  = (const int*)d_in[1];
    const float* imu   = (const float*)d_in[2];
    float* out = (float*)d_out;

    const int B = in_sizes[1];
    const int C = in_sizes[0] / B;
    const int T = in_sizes[2] / (3 * B);

    const int blocks = (B + 3) / 4;
    float* p1 = (float*)d_ws;        // [blocks] CE partial sums
    float* p2 = p1 + blocks;         // [blocks] score partial sums

    if (T == 512 && C == 128) {
        fused_reg_kernel<<<blocks, 256, 0, stream>>>(imu, preds, labels, p1, p2, B);
    } else {
        const size_t smem = (size_t)4 * (size_t)T * 3 * sizeof(float);
        fused_generic_kernel<<<blocks, 256, smem, stream>>>(imu, preds, labels, p1, p2, B, T, C);
    }
    finalize_kernel<<<1, 256, 0, stream>>>(p1, p2, blocks, blocks, out, B);
}